// Round 7
// baseline (7041.457 us; speedup 1.0000x reference)
//
#include <hip/hip_runtime.h>
#include <hip/hip_bf16.h>

#define B_ 64
#define T_ 512
#define O_ 512
#define N_ 2048
#define NWG 64
#define NTHR 512
#define EPSF 1e-5f

typedef __attribute__((ext_vector_type(8))) short short8v;
typedef __attribute__((ext_vector_type(4))) float f32x4;
typedef unsigned short u16;
typedef unsigned long long u64;

__device__ __forceinline__ u16 f2bf(float f) {
    union { float f; unsigned u; } v; v.f = f;
    unsigned r = v.u + 0x7fffu + ((v.u >> 16) & 1u);   // RNE
    return (u16)(r >> 16);
}

// sc1 (agent-scope, LLC-coherent) helpers — relaxed, no fences, no RMW
__device__ __forceinline__ u64 ldg_sc1_u64(const void* p) {
    return __hip_atomic_load((const u64*)p, __ATOMIC_RELAXED, __HIP_MEMORY_SCOPE_AGENT);
}
__device__ __forceinline__ float ldg_sc1_f32(const float* p) {
    return __hip_atomic_load(p, __ATOMIC_RELAXED, __HIP_MEMORY_SCOPE_AGENT);
}
__device__ __forceinline__ void stg_sc1_f32(float* p, float v) {
    __hip_atomic_store(p, v, __ATOMIC_RELAXED, __HIP_MEMORY_SCOPE_AGENT);
}
__device__ __forceinline__ void stg_sc1_u32(unsigned* p, unsigned v) {
    __hip_atomic_store(p, v, __ATOMIC_RELAXED, __HIP_MEMORY_SCOPE_AGENT);
}
__device__ __forceinline__ void stg_sc1_u64(u64* p, u64 v) {
    __hip_atomic_store(p, v, __ATOMIC_RELAXED, __HIP_MEMORY_SCOPE_AGENT);
}

// ---------- init: W fp32 [1024][2048] -> wt bf16 [2048 col][1024 k] ----------
__global__ void k_init_wt(const float* __restrict__ W, u16* __restrict__ wt) {
    __shared__ u16 tile[64][65];
    const int tk = (blockIdx.x >> 5) * 64;
    const int tn = (blockIdx.x & 31) * 64;
    const int r = threadIdx.x >> 6, c = threadIdx.x & 63;
#pragma unroll
    for (int i = 0; i < 16; ++i)
        tile[r + 4 * i][c] = f2bf(W[(size_t)(tk + r + 4 * i) * N_ + tn + c]);
    __syncthreads();
#pragma unroll
    for (int i = 0; i < 16; ++i)
        wt[(size_t)(tn + r + 4 * i) * 1024 + tk + c] = tile[c][r + 4 * i];
}

__global__ void k_zero_flags(unsigned* flags) {
    stg_sc1_u32(flags + threadIdx.x, 0u);
}

// ---------- persistent LN-LSTM: 64 wgs x 512 thr, W resident in VGPRs ----------
__global__ __launch_bounds__(NTHR, 2)
void k_persist(const float* __restrict__ x, const u16* __restrict__ wt,
               const float* __restrict__ bias, const float* __restrict__ lnw,
               const float* __restrict__ lnb, const float* __restrict__ hx,
               const float* __restrict__ cx, u16* hbuf, float* comb,
               float* statsp, unsigned* flags, float* __restrict__ out) {
    __shared__ float sred[4];

    const int tid = threadIdx.x, wgid = blockIdx.x;
    const int w = tid >> 6, l = tid & 63;
    const int rl = l & 15, kg = l >> 4;
    const int rg = w & 3, cg = w >> 2;
    const int r0 = rg * 16;                    // this wave's 16 A/C rows
    const int c0 = wgid * 32 + cg * 16;        // this wave's 16 W cols
    const int myrow = r0 + rl;                 // A row this lane loads
    const int crow0 = r0 + kg * 4;             // first C row of this lane's acc
    const int pidx = wgid * 2 + cg;            // stats-partial slot (0..127)

    // ---- W fragments into registers, once (128 VGPRs) ----
    short8v bw[32];
#pragma unroll
    for (int kc = 0; kc < 32; ++kc)
        bw[kc] = *(const short8v*)(wt + (size_t)(c0 + rl) * 1024 + kc * 32 + kg * 8);

    // ---- phase-2 identity: wg owns batch row b = wgid; thread owns col o = tid ----
    const int b = wgid;
    const int o = tid;
    float lw0 = lnw[o], lw1 = lnw[512 + o], lw2 = lnw[1024 + o], lw3 = lnw[1536 + o];
    float lb0 = lnb[o], lb1 = lnb[512 + o], lb2 = lnb[1024 + o], lb3 = lnb[1536 + o];
    float creg = cx[o];
    {   // h0 into hbuf slot 0 (sc1, packed pairs)
        float h0v = hx[o];
        float hn = __shfl_xor(h0v, 1);
        if (!(tid & 1)) {
            unsigned hp = (unsigned)f2bf(h0v) | ((unsigned)f2bf(hn) << 16);
            stg_sc1_u32((unsigned*)(hbuf + b * O_ + o), hp);
        }
    }
    const float bcol = bias[c0 + rl];

    // ---- one-hop flat barrier ----
    auto arrive = [&](unsigned g) {
        asm volatile("s_waitcnt vmcnt(0)" ::: "memory");
        __syncthreads();
        if (tid == 0) stg_sc1_u32(flags + wgid, g);
    };
    auto wait = [&](unsigned g) {
        if (tid < NWG) {
            while (__hip_atomic_load(flags + tid, __ATOMIC_RELAXED,
                                     __HIP_MEMORY_SCOPE_AGENT) < g) {}
        }
        __syncthreads();
    };

    // x-half chunk: 8 K-slices, fp32 load + convert, B from registers
    auto xhalf8 = [&](int t, int kc0, f32x4& c0a, f32x4& c1a) {
        const float* xrowf = x + (size_t)myrow * (T_ * 512) + (size_t)t * 512;
#pragma unroll
        for (int kc = 0; kc < 8; ++kc) {
            int kk = kc + kc0;
            int kloc = kk * 32 + kg * 8;
            float4 u0 = *(const float4*)(xrowf + kloc);
            float4 u1 = *(const float4*)(xrowf + kloc + 4);
            short8v a;
            a[0] = (short)f2bf(u0.x); a[1] = (short)f2bf(u0.y);
            a[2] = (short)f2bf(u0.z); a[3] = (short)f2bf(u0.w);
            a[4] = (short)f2bf(u1.x); a[5] = (short)f2bf(u1.y);
            a[6] = (short)f2bf(u1.z); a[7] = (short)f2bf(u1.w);
            short8v bb = (kc0 == 0) ? bw[kc] : bw[kc + 8];   // static index
            if (kk & 1) c1a = __builtin_amdgcn_mfma_f32_16x16x32_bf16(a, bb, c1a, 0, 0, 0);
            else        c0a = __builtin_amdgcn_mfma_f32_16x16x32_bf16(a, bb, c0a, 0, 0, 0);
        }
    };
    // h-half: cached loads from rotating slot, B from registers
    auto hhalf = [&](const u16* hslot, f32x4& c0a, f32x4& c1a) {
        const u16* hrow = hslot + (myrow << 9);
#pragma unroll
        for (int kc = 16; kc < 32; ++kc) {
            short8v a = *(const short8v*)(hrow + (kc - 16) * 32 + kg * 8);
            if (kc & 1) c1a = __builtin_amdgcn_mfma_f32_16x16x32_bf16(a, bw[kc], c1a, 0, 0, 0);
            else        c0a = __builtin_amdgcn_mfma_f32_16x16x32_bf16(a, bw[kc], c0a, 0, 0, 0);
        }
    };

    unsigned gen = 1;
    arrive(gen);                       // h0 at LLC
    f32x4 xa0 = {0.f,0.f,0.f,0.f}, xa1 = {0.f,0.f,0.f,0.f};
    xhalf8(0, 0, xa0, xa1);
    xhalf8(0, 8, xa0, xa1);
    wait(gen); gen++;

    for (int t = 0; t < T_; ++t) {
        // ============ phase 1: finish GEMM with h-half ============
        f32x4 ha0 = {0.f,0.f,0.f,0.f}, ha1 = {0.f,0.f,0.f,0.f};
        hhalf(hbuf + (size_t)t * (B_ * O_), ha0, ha1);
        f32x4 acc = (xa0 + xa1) + (ha0 + ha1);

        float sj[4], qj[4];
#pragma unroll
        for (int j = 0; j < 4; ++j) {
            float v = acc[j] + bcol;
            stg_sc1_f32(comb + (size_t)(crow0 + j) * N_ + (c0 + rl), v);
            sj[j] = v; qj[j] = v * v;
        }
#pragma unroll
        for (int m = 1; m < 16; m <<= 1) {
#pragma unroll
            for (int j = 0; j < 4; ++j) {
                sj[j] += __shfl_xor(sj[j], m);
                qj[j] += __shfl_xor(qj[j], m);
            }
        }
        if (rl == 0) {
#pragma unroll
            for (int j = 0; j < 4; ++j) {
                union { float f[2]; u64 q; } p;
                p.f[0] = sj[j]; p.f[1] = qj[j];
                stg_sc1_u64((u64*)(statsp + ((size_t)(crow0 + j) * 128 + pidx) * 2), p.q);
            }
        }

        arrive(gen);                               // comb + stats release
        if (t < T_ - 1) {                          // overlap: first x-chunk of t+1
            xa0 = f32x4{0.f,0.f,0.f,0.f}; xa1 = f32x4{0.f,0.f,0.f,0.f};
            xhalf8(t + 1, 0, xa0, xa1);
        }
        wait(gen); gen++;                          // stats(t) final

        // ============ phase 2: LN + gates + state update ============
        // comb gather first (independent of stats) — overlap LLC RT with reduce
        const float* cb = comb + (size_t)b * N_ + o;
        float cv0 = ldg_sc1_f32(cb);
        float cv1 = ldg_sc1_f32(cb + 512);
        float cv2 = ldg_sc1_f32(cb + 1024);
        float cv3 = ldg_sc1_f32(cb + 1536);

        float s = 0.f, q = 0.f;
        if (tid < 128) {
            union { u64 q64; float f[2]; } p;
            p.q64 = ldg_sc1_u64(statsp + ((size_t)b * 128 + tid) * 2);
            s = p.f[0]; q = p.f[1];
        }
#pragma unroll
        for (int m = 32; m > 0; m >>= 1) {
            s += __shfl_down(s, m);
            q += __shfl_down(q, m);
        }
        if (tid == 0)  { sred[0] = s; sred[1] = q; }
        if (tid == 64) { sred[2] = s; sred[3] = q; }
        __syncthreads();
        float S = sred[0] + sred[2], Q = sred[1] + sred[3];
        float mu = S * (1.0f / 2048.0f);
        float var = Q * (1.0f / 2048.0f) - mu * mu;
        float rstd = rsqrtf(var + EPSF);

        float n0v = (cv0 - mu) * rstd * lw0 + lb0;
        float n1v = (cv1 - mu) * rstd * lw1 + lb1;
        float n2v = (cv2 - mu) * rstd * lw2 + lb2;
        float n3v = (cv3 - mu) * rstd * lw3 + lb3;
        float ig = 1.f / (1.f + __expf(-n0v));
        float fg = 1.f / (1.f + __expf(-n1v));
        float og = 1.f / (1.f + __expf(-n2v));
        float e2 = __expf(-2.f * fabsf(n3v));
        float th = copysignf((1.f - e2) / (1.f + e2), n3v);
        creg = fg * creg + ig * th;
        float h = og * creg;
        __builtin_nontemporal_store(h, out + (size_t)b * (T_ * O_) + (size_t)t * O_ + o);

        if (t == T_ - 1) break;                    // no one consumes the last h

        // h(t+1) into the fresh rotating slot (sc1, packed pairs)
        {
            u16* hW = hbuf + (size_t)(t + 1) * (B_ * O_);
            float hn = __shfl_xor(h, 1);
            if (!(tid & 1)) {
                unsigned hp = (unsigned)f2bf(h) | ((unsigned)f2bf(hn) << 16);
                stg_sc1_u32((unsigned*)(hW + b * O_ + o), hp);
            }
        }

        arrive(gen);                               // h release
        xhalf8(t + 1, 8, xa0, xa1);                // overlap: second x-chunk of t+1
        wait(gen); gen++;                          // h(t+1) visible
    }
}

extern "C" void kernel_launch(void* const* d_in, const int* in_sizes, int n_in,
                              void* d_out, int out_size, void* d_ws, size_t ws_size,
                              hipStream_t stream) {
    const float* x    = (const float*)d_in[0];
    const float* W    = (const float*)d_in[1];
    const float* bias = (const float*)d_in[2];
    const float* lnw  = (const float*)d_in[3];
    const float* lnb  = (const float*)d_in[4];
    const float* hx   = (const float*)d_in[5];
    const float* cx   = (const float*)d_in[6];
    float* out = (float*)d_out;

    char* ws = (char*)d_ws;
    u16*      wt     = (u16*)ws;                      // 4 MiB
    u16*      hbuf   = (u16*)(ws + 4194304);          // 32 MiB (512 rotating h slots)
    float*    statsp = (float*)(ws + 37748736);       // 64 KiB [64 rows][128] float2
    float*    comb   = (float*)(ws + 37814272);       // 512 KiB
    unsigned* flags  = (unsigned*)(ws + 38338560);    // 1 KiB
    // total ~38.34 MB — within proven ws budget (r6 ran identically sized)

    k_init_wt<<<512, 256, 0, stream>>>(W, wt);
    k_zero_flags<<<1, 256, 0, stream>>>(flags);
    k_persist<<<NWG, NTHR, 0, stream>>>(x, wt, bias, lnw, lnb, hx, cx,
                                        hbuf, comb, statsp, flags, out);
}